// Round 13
// baseline (637.373 us; speedup 1.0000x reference)
//
#include <hip/hip_runtime.h>

#define B 100
#define R 1152
#define C 10
#define O 16
#define I 8
#define RI 9216
#define RC2 2304        // x0 row length in float4
#define RCHUNK 16
#define NRC 72          // R / RCHUNK
#define KCH 128         // RCHUNK*I

#define NB 720          // routing team
#define GRID 1024       // + 304 streamers; 22.6KB LDS, <=128 VGPR -> all resident

#define T1c (-0.075410217f)
#define T3c (0.062207676f)

typedef float f4raw __attribute__((ext_vector_type(4)));
static __device__ __forceinline__ void nt_store4(const float4& v, float4* p) {
    __builtin_nontemporal_store(*(const f4raw*)&v, (f4raw*)p);
}

// ws float offsets
#define WS_CNT  0                  // barrier counter (64B pad), memset per call
#define WS_BCOL 64                 // [c][r] 11520
#define WS_CSM  11584              // [r][c] 11520
#define WS_PART 23104              // [c][72][100][16] = 1152000
#define WS_VOB  1175104            // [c*16+o][b] 16000

// out float4 offsets
#define O_VJ 0
#define O_CF 4000
#define O_WB 292000
#define O_SQ 37156000
#define O_X1 39460000
#define O_X2 39690400
#define O_SM 39710000

// stream units (80KB each): Wb 7200 | squashed_u 563 | x1 57 | x2 5
#define U_WB 7200
#define U_SQ 563
#define U_X1 57
#define U_TOT 7825
#define STREAM_BASE 3873           // 304 streamers x 13 units = 3952 -> 3873..7824

__device__ void stream_unit(int u, const float4* __restrict__ W4,
                            const float4* __restrict__ x04,
                            const float4* __restrict__ x14,
                            const float4* __restrict__ x24,
                            float4* __restrict__ out) {
    const int t = threadIdx.x;
    if (u < U_WB) {
        int wchunk = u % 1440, bg = u / 1440;
        int idx = wchunk * 256 + t;
        float4 v = W4[idx];
        float4* dst = out + O_WB + (size_t)bg * 20 * 368640 + idx;
        #pragma unroll
        for (int b = 0; b < 20; b++) { nt_store4(v, dst); dst += 368640; }
    } else if (u < U_WB + U_SQ) {
        int s = u - U_WB;
        int m0 = s * 4096, m1 = m0 + 4096; if (m1 > 2304000) m1 = 2304000;
        for (int m = m0 + t; m < m1; m += 256) {
            float4 v = x04[(m / 20) * 2 + (m & 1)];
            nt_store4(v, &out[O_SQ + m]);
        }
    } else if (u < U_WB + U_SQ + U_X1) {
        int s = u - U_WB - U_SQ;
        int m0 = s * 4096, m1 = m0 + 4096; if (m1 > 230400) m1 = 230400;
        for (int m = m0 + t; m < m1; m += 256) nt_store4(x14[m], &out[O_X1 + m]);
    } else {
        int s = u - U_WB - U_SQ - U_X1;
        int m0 = s * 4096, m1 = m0 + 4096; if (m1 > 19600) m1 = 19600;
        for (int m = m0 + t; m < m1; m += 256) nt_store4(x24[m], &out[O_X2 + m]);
    }
}

// ---- barrier: release arrival, RELAXED polling (no cache maintenance), one acquire on exit ----
static __device__ __forceinline__ void rbar(unsigned* cnt, unsigned target) {
    __syncthreads();
    if (threadIdx.x == 0) {
        __hip_atomic_fetch_add(cnt, 1u, __ATOMIC_RELEASE, __HIP_MEMORY_SCOPE_AGENT);
        while (__hip_atomic_load(cnt, __ATOMIC_RELAXED, __HIP_MEMORY_SCOPE_AGENT) < target)
            __builtin_amdgcn_s_sleep(16);
        __builtin_amdgcn_fence(__ATOMIC_ACQUIRE, "agent");
    }
    __syncthreads();
}

#define TPP(k2, b) tpp[(k2) * 104 + (b)]

// ---- G phase: R8's k_gemm body (reads x0 directly, writes PART [+CSM @it2]) ----
static __device__ void phase_g(int bk, int t, const float* __restrict__ Wg,
                               const float4* __restrict__ x04,
                               float* __restrict__ ws, int it, float* smem) {
    const int rc = bk % NRC, c = bk / NRC;
    const int r0 = rc * RCHUNK;
    float* red = smem;            // 256
    float* cw  = smem + 256;      // 16
    float* lw  = smem + 272;      // 2048
    float2* tpp = (float2*)(smem + 2320);   // [16][104]

    if (it > 0) {
        const float* bcol = ws + WS_BCOL + c * R;
        float lm = -3.4e38f;
        for (int r = t; r < R; r += 256) lm = fmaxf(lm, bcol[r]);
        red[t] = lm; __syncthreads();
        for (int s = 128; s > 0; s >>= 1) { if (t < s) red[t] = fmaxf(red[t], red[t + s]); __syncthreads(); }
        const float m = red[0]; __syncthreads();
        float ls = 0.f;
        for (int r = t; r < R; r += 256) ls += expf(bcol[r] - m);
        red[t] = ls; __syncthreads();
        for (int s = 128; s > 0; s >>= 1) { if (t < s) red[t] += red[t + s]; __syncthreads(); }
        const float sinv = 1.f / red[0];
        if (t < RCHUNK) cw[t] = expf(bcol[r0 + t] - m) * sinv;
        if (it == 2 && rc == 0) {
            for (int r = t; r < R; r += 256)
                ws[WS_CSM + r * C + c] = expf(bcol[r] - m) * sinv;
        }
    } else {
        if (t < RCHUNK) cw[t] = 1.0f / 1152.0f;
    }
    __syncthreads();

    for (int j = t; j < KCH * O; j += 256) {
        int rr = j >> 7;
        int rem = j & 127;
        int o = rem >> 3, i = rem & 7;
        lw[((rr * I + i) << 4) + o] = cw[rr] * Wg[((size_t)(r0 + rr) * C + c) * 128 + rem];
    }

    const int bl = t & 63, og = t >> 6;
    int b2 = bl + 64; if (b2 > 103) b2 = 103;
    float4 a0 = {0, 0, 0, 0}, a1 = {0, 0, 0, 0};
    for (int p = 0; p < 4; p++) {
        __syncthreads();
        int colbase = r0 * 2 + p * 8;
        for (int e = t; e < 800; e += 256) {
            int b = e >> 3, q = e & 7;
            float4 v = x04[(size_t)b * RC2 + colbase + q];
            TPP(q * 2 + 0, b) = make_float2(v.x, v.y);
            TPP(q * 2 + 1, b) = make_float2(v.z, v.w);
        }
        if (p == 0 && t < 64) TPP(t >> 2, 100 + (t & 3)) = make_float2(0.f, 0.f);
        __syncthreads();
        const float4* lwp = (const float4*)lw + p * 128;
        #pragma unroll 8
        for (int k2 = 0; k2 < 16; k2++) {
            float2 xv0 = TPP(k2, bl);
            float2 xv1 = TPP(k2, b2);
            float4 wa = lwp[k2 * 8 + og];
            float4 wb = lwp[k2 * 8 + 4 + og];
            a0.x += xv0.x * wa.x + xv0.y * wb.x;
            a0.y += xv0.x * wa.y + xv0.y * wb.y;
            a0.z += xv0.x * wa.z + xv0.y * wb.z;
            a0.w += xv0.x * wa.w + xv0.y * wb.w;
            a1.x += xv1.x * wa.x + xv1.y * wb.x;
            a1.y += xv1.x * wa.y + xv1.y * wb.y;
            a1.z += xv1.x * wa.z + xv1.y * wb.z;
            a1.w += xv1.x * wa.w + xv1.y * wb.w;
        }
    }
    float4* part4 = (float4*)(ws + WS_PART);
    int base = ((c * NRC + rc) * B + bl) * 4 + og;
    part4[base] = a0;
    if (bl < 36) part4[base + 256] = a1;
    __syncthreads();
}

// ---- S phase: reduce 72 partials + squash -> VOB ----
static __device__ void phase_s(int b, int t, float* __restrict__ ws, float* smem) {
    float* sl = smem;        // 160
    float* nf = smem + 160;  // 10
    if (t < 160) {
        int c = t >> 4, o = t & 15;
        float s = 0.f;
        const float* p = ws + WS_PART + ((size_t)c * NRC * B + b) * 16 + o;
        #pragma unroll 8
        for (int rc = 0; rc < NRC; rc++) s += p[rc * 1600];
        sl[t] = s;
    }
    __syncthreads();
    if (t < C) {
        float fv[C];
        #pragma unroll
        for (int c2 = 0; c2 < C; c2++) fv[c2] = sl[c2 * O];
        float mine = sl[t * O];
        int rank = 0, i1 = 0, i2 = 0, i3 = 0;
        #pragma unroll
        for (int c2 = 0; c2 < C; c2++) {
            rank += (fv[c2] < mine) || (fv[c2] == mine && c2 < t);
            i1 += fv[c2] < T1c;
            i2 += fv[c2] < 0.0f;
            i3 += fv[c2] < T3c;
        }
        float nv = mine;
        if (i1 > 0 && rank < i1 - 1)                               nv = -0.074520095f * mine + 0.349297946f;
        else if (i2 > 0 && i2 > i1 && rank >= i1 && rank < i2 - 1) nv = -0.534473989f * mine + 0.27196494f;
        else if (i3 > 0 && i3 > i2 && rank >= i2 && rank < i3 - 1) nv = 0.637642944f * mine + 0.295330779f;
        else if (i3 < C && rank >= i3 && rank < C - 1)             nv = 0.169344703f * mine + 0.353784456f;
        nf[t] = nv;
    }
    __syncthreads();
    if (t < 160) {
        int c = t >> 4, o = t & 15;
        float smut = (o == 0) ? nf[c] : sl[t];
        ws[WS_VOB + t * B + b] = nf[c] * smut;
    }
    __syncthreads();
}

// ---- A phase unit (one r): R8's k_agree body ----
static __device__ void phase_a_one(int r, int t, const float* __restrict__ Wg,
                                   const float4* __restrict__ x04,
                                   float* __restrict__ ws, int it, float* smem) {
    float* vt  = smem;          // 3200
    float* xs  = smem + 3200;   // 800
    float* arr = smem + 4000;   // 1280
    const float4* vob4 = (const float4*)(ws + WS_VOB);
    __syncthreads();   // protect xs/arr from previous unit
    if (t < 200) {
        int b = t >> 1, half = t & 1;
        float4 v = x04[(size_t)b * RC2 + r * 2 + half];
        xs[(half * 4 + 0) * B + b] = v.x; xs[(half * 4 + 1) * B + b] = v.y;
        xs[(half * 4 + 2) * B + b] = v.z; xs[(half * 4 + 3) * B + b] = v.w;
    }
    const int i = t & 7, co0 = t >> 3;
    const float4* xs4 = (const float4*)(xs + i * B);
    const float4* vt4 = (const float4*)(vt + co0 * B);
    float4* vtw = (float4*)vt;
    for (int ch = 0; ch < 5; ch++) {
        __syncthreads();
        for (int j = t; j < 800; j += 256) vtw[j] = vob4[ch * 800 + j];
        __syncthreads();
        float q = 0.f;
        #pragma unroll
        for (int b4 = 0; b4 < 25; b4++) {
            float4 xv = xs4[b4];
            float4 vv = vt4[b4];
            q += xv.x * vv.x + xv.y * vv.y + xv.z * vv.z + xv.w * vv.w;
        }
        int co = ch * 32 + co0;
        arr[co * I + i] = q * Wg[(size_t)r * 1280 + co * I + i];
    }
    __syncthreads();
    if (t < C) {
        const float4* a4 = (const float4*)(arr + t * 128);
        float d = 0.f;
        #pragma unroll
        for (int m2 = 0; m2 < 32; m2++) { float4 v4 = a4[m2]; d += v4.x + v4.y + v4.z + v4.w; }
        float* dst = ws + WS_BCOL + t * R + r;
        float val = d * (1.0f / B);
        if (it == 0) *dst = val; else *dst += val;
    }
}

// ---- the single kernel ----
__global__ __launch_bounds__(256, 4) void k_all(const float* __restrict__ x0,
                                                const float* __restrict__ x1,
                                                const float* __restrict__ x2,
                                                const float* __restrict__ Wg,
                                                float* __restrict__ ws,
                                                float4* __restrict__ out) {
    const int bk = blockIdx.x, t = threadIdx.x;
    __shared__ __align__(16) float smem[5664];
    unsigned* cnt = (unsigned*)ws;
    const float4* W4  = (const float4*)Wg;
    const float4* x04 = (const float4*)x0;
    const float4* x14 = (const float4*)x1;
    const float4* x24 = (const float4*)x2;

    if (bk >= NB) {   // streamers: free-run the top 3952 units
        int s = bk - NB;
        #pragma unroll 1
        for (int n = 0; n < 13; n++)
            stream_unit(STREAM_BASE + s * 13 + n, W4, x04, x14, x24, out);
        return;
    }

    // routing chain: G0 S0 A0 G1 S1 A1 G2 final
    phase_g(bk, t, Wg, x04, ws, 0, smem);
    rbar(cnt, NB * 1);
    if (bk < B) phase_s(bk, t, ws, smem);
    rbar(cnt, NB * 2);
    phase_a_one(bk, t, Wg, x04, ws, 0, smem);
    if (bk < 432) phase_a_one(720 + bk, t, Wg, x04, ws, 0, smem);
    rbar(cnt, NB * 3);
    phase_g(bk, t, Wg, x04, ws, 1, smem);
    rbar(cnt, NB * 4);
    if (bk < B) phase_s(bk, t, ws, smem);
    rbar(cnt, NB * 5);
    phase_a_one(bk, t, Wg, x04, ws, 1, smem);
    if (bk < 432) phase_a_one(720 + bk, t, Wg, x04, ws, 1, smem);
    rbar(cnt, NB * 6);
    phase_g(bk, t, Wg, x04, ws, 2, smem);
    rbar(cnt, NB * 7);

    // final: squash(G2) -> v_j/s_mut (blocks 0..99), c_full, then drain
    if (bk < B) {
        const int b = bk;
        float* sl = smem;
        float* nf = smem + 160;
        float* vv = smem + 176;
        float* sm = smem + 336;
        if (t < 160) {
            int c = t >> 4, o = t & 15;
            float s = 0.f;
            const float* p = ws + WS_PART + ((size_t)c * NRC * B + b) * 16 + o;
            #pragma unroll 8
            for (int rc = 0; rc < NRC; rc++) s += p[rc * 1600];
            sl[t] = s;
        }
        __syncthreads();
        if (t < C) {
            float fv[C];
            #pragma unroll
            for (int c2 = 0; c2 < C; c2++) fv[c2] = sl[c2 * O];
            float mine = sl[t * O];
            int rank = 0, i1 = 0, i2 = 0, i3 = 0;
            #pragma unroll
            for (int c2 = 0; c2 < C; c2++) {
                rank += (fv[c2] < mine) || (fv[c2] == mine && c2 < t);
                i1 += fv[c2] < T1c;
                i2 += fv[c2] < 0.0f;
                i3 += fv[c2] < T3c;
            }
            float nv = mine;
            if (i1 > 0 && rank < i1 - 1)                               nv = -0.074520095f * mine + 0.349297946f;
            else if (i2 > 0 && i2 > i1 && rank >= i1 && rank < i2 - 1) nv = -0.534473989f * mine + 0.27196494f;
            else if (i3 > 0 && i3 > i2 && rank >= i2 && rank < i3 - 1) nv = 0.637642944f * mine + 0.295330779f;
            else if (i3 < C && rank >= i3 && rank < C - 1)             nv = 0.169344703f * mine + 0.353784456f;
            nf[t] = nv;
        }
        __syncthreads();
        if (t < 160) {
            int c = t >> 4, o = t & 15;
            float smut = (o == 0) ? nf[c] : sl[t];
            sm[t] = smut;
            vv[t] = nf[c] * smut;
        }
        __syncthreads();
        if (t < 40) {
            nt_store4(((const float4*)vv)[t], &out[O_VJ + b * 40 + t]);
            nt_store4(((const float4*)sm)[t], &out[O_SM + b * 40 + t]);
        }
    }
    const float4* cs4 = (const float4*)(ws + WS_CSM);
    for (int j = bk * 256 + t; j < 288000; j += NB * 256)
        nt_store4(cs4[j % 2880], &out[O_CF + j]);
    #pragma unroll 1
    for (int n = 0; n < 7; n++) {
        int u = bk * 7 + n;
        if (u < STREAM_BASE) stream_unit(u, W4, x04, x14, x24, out);
    }
}

extern "C" void kernel_launch(void* const* d_in, const int* in_sizes, int n_in,
                              void* d_out, int out_size, void* d_ws, size_t ws_size,
                              hipStream_t stream) {
    (void)in_sizes; (void)n_in; (void)out_size; (void)ws_size;
    const float* x0 = (const float*)d_in[0];
    const float* x1 = (const float*)d_in[1];
    const float* x2 = (const float*)d_in[2];
    const float* Wg = (const float*)d_in[3];
    float* ws = (float*)d_ws;
    float4* out = (float4*)d_out;

    hipMemsetAsync(d_ws, 0, 256, stream);   // barrier counter
    hipLaunchKernelGGL(k_all, dim3(GRID), dim3(256), 0, stream, x0, x1, x2, Wg, ws, out);
}

// Round 14
// 197.192 us; speedup vs baseline: 3.2323x; 3.2323x over previous
//
#include <hip/hip_runtime.h>

#define B 100
#define R 1152
#define C 10
#define O 16
#define I 8
#define RI 9216
#define RC2 2304        // x0 row length in float4
#define RCHUNK 16
#define NRC 72          // R / RCHUNK
#define KCH 128         // RCHUNK*I

#define T1c (-0.075410217f)
#define T3c (0.062207676f)

typedef float f4raw __attribute__((ext_vector_type(4)));
static __device__ __forceinline__ void nt_store4(const float4& v, float4* p) {
    __builtin_nontemporal_store(*(const f4raw*)&v, (f4raw*)p);
}

// ws float offsets
#define WS_BCOL 0                  // [c][r] 11520
#define WS_CSM  11520              // [r][c] 11520
#define WS_PART 23040              // [c][rc][b][o] 10*72*100*16 = 1152000
#define WS_VOB  1175040            // [c*16+o][b] 16000 (coalesced A staging)

// out float4 offsets
#define O_VJ 0
#define O_CF 4000
#define O_WB 292000
#define O_SQ 37156000
#define O_X1 39460000
#define O_X2 39690400
#define O_SM 39710000

// static stream units (80KB each): Wb 7200 | squashed_u 563 | x1 57 | x2 5
#define U_WB 7200
#define U_SQ 563
#define U_X1 57
#define U_TOT 7825

__device__ void stream_unit(int u, const float4* __restrict__ W4,
                            const float4* __restrict__ x04,
                            const float4* __restrict__ x14,
                            const float4* __restrict__ x24,
                            float4* __restrict__ out) {
    const int t = threadIdx.x;
    if (u < U_WB) {
        int wchunk = u % 1440, bg = u / 1440;
        int idx = wchunk * 256 + t;
        float4 v = W4[idx];
        float4* dst = out + O_WB + (size_t)bg * 20 * 368640 + idx;
        #pragma unroll
        for (int b = 0; b < 20; b++) { nt_store4(v, dst); dst += 368640; }
    } else if (u < U_WB + U_SQ) {
        int s = u - U_WB;
        int m0 = s * 4096, m1 = m0 + 4096; if (m1 > 2304000) m1 = 2304000;
        for (int m = m0 + t; m < m1; m += 256) {
            float4 v = x04[(m / 20) * 2 + (m & 1)];   // squashed_u = x0 bcast over c
            nt_store4(v, &out[O_SQ + m]);
        }
    } else if (u < U_WB + U_SQ + U_X1) {
        int s = u - U_WB - U_SQ;
        int m0 = s * 4096, m1 = m0 + 4096; if (m1 > 230400) m1 = 230400;
        for (int m = m0 + t; m < m1; m += 256) nt_store4(x14[m], &out[O_X1 + m]);
    } else {
        int s = u - U_WB - U_SQ - U_X1;
        int m0 = s * 4096, m1 = m0 + 4096; if (m1 > 19600) m1 = 19600;
        for (int m = m0 + t; m < m1; m += 256) nt_store4(x24[m], &out[O_X2 + m]);
    }
}

// ---------- G: s_j partial GEMM, softmax fused; 4-phase x0 tiles (22KB LDS) ----------
__global__ __launch_bounds__(256) void k_gemm(const float* __restrict__ Wg,
                                              const float* __restrict__ x0,
                                              float* __restrict__ ws,
                                              const float4* __restrict__ x14,
                                              const float4* __restrict__ x24,
                                              float4* __restrict__ out,
                                              int it, int ubase) {
    const int t = threadIdx.x;
    const float4* x04 = (const float4*)x0;
    if (blockIdx.x >= 720) {
        stream_unit(ubase + (blockIdx.x - 720), (const float4*)Wg, x04, x14, x24, out);
        return;
    }
    const int rc = blockIdx.x % NRC, c = blockIdx.x / NRC;
    const int r0 = rc * RCHUNK;
    __shared__ float red[256];
    __shared__ float cw[RCHUNK];
    __shared__ __align__(16) float lw[KCH * O];   // 2048: [k][o], c-weight folded
    __shared__ float2 tpp[16][104];               // [k2 local][b]; 13.3 KB

    if (it > 0) {
        const float* bcol = ws + WS_BCOL + c * R;
        float lm = -3.4e38f;
        for (int r = t; r < R; r += 256) lm = fmaxf(lm, bcol[r]);
        red[t] = lm; __syncthreads();
        for (int s = 128; s > 0; s >>= 1) { if (t < s) red[t] = fmaxf(red[t], red[t + s]); __syncthreads(); }
        const float m = red[0]; __syncthreads();
        float ls = 0.f;
        for (int r = t; r < R; r += 256) ls += expf(bcol[r] - m);
        red[t] = ls; __syncthreads();
        for (int s = 128; s > 0; s >>= 1) { if (t < s) red[t] += red[t + s]; __syncthreads(); }
        const float sinv = 1.f / red[0];
        if (t < RCHUNK) cw[t] = expf(bcol[r0 + t] - m) * sinv;
        if (it == 2 && rc == 0) {   // final c_ij feeds the c_full output
            for (int r = t; r < R; r += 256)
                ws[WS_CSM + r * C + c] = expf(bcol[r] - m) * sinv;
        }
    } else {
        if (t < RCHUNK) cw[t] = 1.0f / 1152.0f;   // softmax of zeros
    }
    __syncthreads();

    // stage c-weighted W slice: lw[(rr*8+i)*16+o] = cw[rr]*W[r0+rr,c,o,i]
    for (int j = t; j < KCH * O; j += 256) {
        int rr = j >> 7;
        int rem = j & 127;            // o*8+i
        int o = rem >> 3, i = rem & 7;
        lw[((rr * I + i) << 4) + o] = cw[rr] * Wg[((size_t)(r0 + rr) * C + c) * 128 + rem];
    }

    const int bl = t & 63, og = t >> 6;
    int b2 = bl + 64; if (b2 > 103) b2 = 103;    // clamps into zero pad
    float4 a0 = {0, 0, 0, 0}, a1 = {0, 0, 0, 0};
    for (int p = 0; p < 4; p++) {
        __syncthreads();   // covers lw staging (p0) / prev-phase reads
        int colbase = r0 * 2 + p * 8;            // 8 f4 (=32 k) per phase
        for (int e = t; e < 800; e += 256) {
            int b = e >> 3, q = e & 7;
            float4 v = x04[(size_t)b * RC2 + colbase + q];
            tpp[q * 2 + 0][b] = make_float2(v.x, v.y);
            tpp[q * 2 + 1][b] = make_float2(v.z, v.w);
        }
        if (p == 0 && t < 64) tpp[t >> 2][100 + (t & 3)] = make_float2(0.f, 0.f);
        __syncthreads();
        const float4* lwp = (const float4*)lw + p * 128;
        #pragma unroll 8
        for (int k2 = 0; k2 < 16; k2++) {
            float2 xv0 = tpp[k2][bl];
            float2 xv1 = tpp[k2][b2];
            float4 wa = lwp[k2 * 8 + og];
            float4 wb = lwp[k2 * 8 + 4 + og];
            a0.x += xv0.x * wa.x + xv0.y * wb.x;
            a0.y += xv0.x * wa.y + xv0.y * wb.y;
            a0.z += xv0.x * wa.z + xv0.y * wb.z;
            a0.w += xv0.x * wa.w + xv0.y * wb.w;
            a1.x += xv1.x * wa.x + xv1.y * wb.x;
            a1.y += xv1.x * wa.y + xv1.y * wb.y;
            a1.z += xv1.x * wa.z + xv1.y * wb.z;
            a1.w += xv1.x * wa.w + xv1.y * wb.w;
        }
    }
    float4* part4 = (float4*)(ws + WS_PART);
    int base = ((c * NRC + rc) * B + bl) * 4 + og;
    part4[base] = a0;
    if (bl < 36) part4[base + 256] = a1;
}

// ---------- S: reduce 72 partials + squash -> VOB only (A's input) ----------
__global__ __launch_bounds__(256) void k_squash(float* __restrict__ ws,
                                                const float* __restrict__ Wg,
                                                const float* __restrict__ x0,
                                                const float4* __restrict__ x14,
                                                const float4* __restrict__ x24,
                                                float4* __restrict__ out, int ubase) {
    const int t = threadIdx.x;
    if (blockIdx.x >= B) {
        stream_unit(ubase + (blockIdx.x - B), (const float4*)Wg, (const float4*)x0, x14, x24, out);
        return;
    }
    const int b = blockIdx.x;
    __shared__ float sl[160];
    __shared__ float nf[C];
    if (t < 160) {
        int c = t >> 4, o = t & 15;
        float s = 0.f;
        const float* p = ws + WS_PART + ((size_t)c * NRC * B + b) * 16 + o;
        #pragma unroll 8
        for (int rc = 0; rc < NRC; rc++) s += p[rc * 1600];
        sl[t] = s;
    }
    __syncthreads();
    if (t < C) {
        float fv[C];
        #pragma unroll
        for (int c2 = 0; c2 < C; c2++) fv[c2] = sl[c2 * O];
        float mine = sl[t * O];
        int rank = 0, i1 = 0, i2 = 0, i3 = 0;
        #pragma unroll
        for (int c2 = 0; c2 < C; c2++) {
            rank += (fv[c2] < mine) || (fv[c2] == mine && c2 < t);
            i1 += fv[c2] < T1c;
            i2 += fv[c2] < 0.0f;
            i3 += fv[c2] < T3c;
        }
        float nv = mine;
        if (i1 > 0 && rank < i1 - 1)                               nv = -0.074520095f * mine + 0.349297946f;
        else if (i2 > 0 && i2 > i1 && rank >= i1 && rank < i2 - 1) nv = -0.534473989f * mine + 0.27196494f;
        else if (i3 > 0 && i3 > i2 && rank >= i2 && rank < i3 - 1) nv = 0.637642944f * mine + 0.295330779f;
        else if (i3 < C && rank >= i3 && rank < C - 1)             nv = 0.169344703f * mine + 0.353784456f;
        nf[t] = nv;
    }
    __syncthreads();
    if (t < 160) {
        int c = t >> 4, o = t & 15;
        float smut = (o == 0) ? nf[c] : sl[t];
        ws[WS_VOB + t * B + b] = nf[c] * smut;   // [c*16+o][b]
    }
}

// ---------- A: agreement; one block per r; coalesced+vectorized v staging ----------
__global__ __launch_bounds__(256) void k_agree(const float* __restrict__ Wg,
                                               const float* __restrict__ x0,
                                               float* __restrict__ ws,
                                               const float4* __restrict__ x14,
                                               const float4* __restrict__ x24,
                                               float4* __restrict__ out,
                                               int it, int ubase) {
    const int t = threadIdx.x;
    if (blockIdx.x >= R) {
        stream_unit(ubase + (blockIdx.x - R), (const float4*)Wg, (const float4*)x0, x14, x24, out);
        return;
    }
    const int r = blockIdx.x;
    __shared__ __align__(16) float vt[3200];   // [cc][b], one 32-co chunk
    __shared__ __align__(16) float xs[800];    // [i][b]
    __shared__ __align__(16) float arr[1280];  // [co][i]
    const float4* x04 = (const float4*)x0;
    const float4* vob4 = (const float4*)(ws + WS_VOB);
    if (t < 200) {
        int b = t >> 1, half = t & 1;
        float4 v = x04[(size_t)b * RC2 + r * 2 + half];
        xs[(half * 4 + 0) * B + b] = v.x; xs[(half * 4 + 1) * B + b] = v.y;
        xs[(half * 4 + 2) * B + b] = v.z; xs[(half * 4 + 3) * B + b] = v.w;
    }
    const int i = t & 7, co0 = t >> 3;
    const float4* xs4 = (const float4*)(xs + i * B);
    const float4* vt4 = (const float4*)(vt + co0 * B);
    float4* vtw = (float4*)vt;
    for (int ch = 0; ch < 5; ch++) {
        __syncthreads();
        for (int j = t; j < 800; j += 256) vtw[j] = vob4[ch * 800 + j];  // coalesced f4
        __syncthreads();
        float q = 0.f;
        #pragma unroll
        for (int b4 = 0; b4 < 25; b4++) {
            float4 xv = xs4[b4];
            float4 vv = vt4[b4];
            q += xv.x * vv.x + xv.y * vv.y + xv.z * vv.z + xv.w * vv.w;
        }
        int co = ch * 32 + co0;
        arr[co * I + i] = q * Wg[(size_t)r * 1280 + co * I + i];
    }
    __syncthreads();
    if (t < C) {
        const float4* a4 = (const float4*)(arr + t * 128);
        float d = 0.f;
        #pragma unroll
        for (int m2 = 0; m2 < 32; m2++) { float4 v4 = a4[m2]; d += v4.x + v4.y + v4.z + v4.w; }
        float* dst = ws + WS_BCOL + t * R + r;
        float val = d * (1.0f / B);
        if (it == 0) *dst = val; else *dst += val;
    }
}

// ---------- OUT: final squash (blocks 0..99) + c_full + remaining stream units ----------
__global__ __launch_bounds__(256) void k_out(const float* __restrict__ x0,
                                             const float* __restrict__ x1,
                                             const float* __restrict__ x2,
                                             float* __restrict__ ws,
                                             const float* __restrict__ Wg,
                                             float4* __restrict__ out) {
    const int bid = blockIdx.x, t = threadIdx.x;
    if (bid < B) {   // final squash from G2 partials -> v_j + s_mut straight to out
        const int b = bid;
        __shared__ float sl[160];
        __shared__ float nf[C];
        __shared__ __align__(16) float vv[160];
        __shared__ __align__(16) float sm[160];
        if (t < 160) {
            int c = t >> 4, o = t & 15;
            float s = 0.f;
            const float* p = ws + WS_PART + ((size_t)c * NRC * B + b) * 16 + o;
            #pragma unroll 8
            for (int rc = 0; rc < NRC; rc++) s += p[rc * 1600];
            sl[t] = s;
        }
        __syncthreads();
        if (t < C) {
            float fv[C];
            #pragma unroll
            for (int c2 = 0; c2 < C; c2++) fv[c2] = sl[c2 * O];
            float mine = sl[t * O];
            int rank = 0, i1 = 0, i2 = 0, i3 = 0;
            #pragma unroll
            for (int c2 = 0; c2 < C; c2++) {
                rank += (fv[c2] < mine) || (fv[c2] == mine && c2 < t);
                i1 += fv[c2] < T1c;
                i2 += fv[c2] < 0.0f;
                i3 += fv[c2] < T3c;
            }
            float nv = mine;
            if (i1 > 0 && rank < i1 - 1)                               nv = -0.074520095f * mine + 0.349297946f;
            else if (i2 > 0 && i2 > i1 && rank >= i1 && rank < i2 - 1) nv = -0.534473989f * mine + 0.27196494f;
            else if (i3 > 0 && i3 > i2 && rank >= i2 && rank < i3 - 1) nv = 0.637642944f * mine + 0.295330779f;
            else if (i3 < C && rank >= i3 && rank < C - 1)             nv = 0.169344703f * mine + 0.353784456f;
            nf[t] = nv;
        }
        __syncthreads();
        if (t < 160) {
            int c = t >> 4, o = t & 15;
            float smut = (o == 0) ? nf[c] : sl[t];
            sm[t] = smut;
            vv[t] = nf[c] * smut;
        }
        __syncthreads();
        if (t < 40) {
            nt_store4(((const float4*)vv)[t], &out[O_VJ + b * 40 + t]);
            nt_store4(((const float4*)sm)[t], &out[O_SM + b * 40 + t]);
        }
    }
    // c_full (CSM repeated per b)
    const float4* cs4 = (const float4*)(ws + WS_CSM);
    for (int j = bid * 256 + t; j < 288000; j += 2048 * 256)
        nt_store4(cs4[j % 2880], &out[O_CF + j]);
    // remaining stream units (5380..7824)
    for (int k = 0; k < 2; k++) {
        int u = 5380 + bid + k * 2048;
        if (u < U_TOT)
            stream_unit(u, (const float4*)Wg, (const float4*)x0,
                        (const float4*)x1, (const float4*)x2, out);
    }
}

extern "C" void kernel_launch(void* const* d_in, const int* in_sizes, int n_in,
                              void* d_out, int out_size, void* d_ws, size_t ws_size,
                              hipStream_t stream) {
    (void)in_sizes; (void)n_in; (void)out_size; (void)ws_size;
    const float* x0 = (const float*)d_in[0];
    const float* x1 = (const float*)d_in[1];
    const float* x2 = (const float*)d_in[2];
    const float* Wg = (const float*)d_in[3];
    const float4* x14 = (const float4*)x1;
    const float4* x24 = (const float4*)x2;
    float* ws = (float*)d_ws;
    float4* out = (float4*)d_out;

    // 8 launches; maximal riders within single-round co-residency.
    // bases: G0=0(1000) S0=1000(550) A0=1550(640) G1=2190(1000)
    // S1=3190(550) A1=3740(640) G2=4380(1000); k_out 5380..7824
    hipLaunchKernelGGL(k_gemm,   dim3(720 + 1000), dim3(256), 0, stream, Wg, x0, ws, x14, x24, out, 0, 0);
    hipLaunchKernelGGL(k_squash, dim3(100 + 550),  dim3(256), 0, stream, ws, Wg, x0, x14, x24, out, 1000);
    hipLaunchKernelGGL(k_agree,  dim3(1152 + 640), dim3(256), 0, stream, Wg, x0, ws, x14, x24, out, 0, 1550);
    hipLaunchKernelGGL(k_gemm,   dim3(720 + 1000), dim3(256), 0, stream, Wg, x0, ws, x14, x24, out, 1, 2190);
    hipLaunchKernelGGL(k_squash, dim3(100 + 550),  dim3(256), 0, stream, ws, Wg, x0, x14, x24, out, 3190);
    hipLaunchKernelGGL(k_agree,  dim3(1152 + 640), dim3(256), 0, stream, Wg, x0, ws, x14, x24, out, 1, 3740);
    hipLaunchKernelGGL(k_gemm,   dim3(720 + 1000), dim3(256), 0, stream, Wg, x0, ws, x14, x24, out, 2, 4380);
    hipLaunchKernelGGL(k_out,    dim3(2048), dim3(256), 0, stream, x0, x1, x2, ws, Wg, out);
}